// Round 1
// baseline (62.918 us; speedup 1.0000x reference)
//
#include <hip/hip_runtime.h>

__device__ __forceinline__ float relu_f(float v) { return fmaxf(v, 0.0f); }

// Exact replica of the reference _hat() in fp32.
__device__ __forceinline__ float hatf(float xf, float xm, float xc, float xp) {
    float left  = relu_f(1.0f - relu_f(xc - xf) / (xc - xm));
    float right = relu_f(1.0f - relu_f(xf - xc) / (xp - xc));
    return left + right - 1.0f;
}

__global__ __launch_bounds__(256) void MeshNN_23330262352119_kernel(
        const float* __restrict__ x,
        const float* __restrict__ coords,
        const float* __restrict__ w_uu,
        const float* __restrict__ w_dd,
        float* __restrict__ out,
        int n, int np) {
    extern __shared__ float smem[];
    float* sc = smem;          // np node coords
    float* sw = smem + np;     // np-2 interior weights
    for (int i = threadIdx.x; i < np; i += blockDim.x)     sc[i] = coords[i];
    for (int i = threadIdx.x; i < np - 2; i += blockDim.x) sw[i] = w_uu[i];
    __syncthreads();

    const float c0   = sc[0];
    const float cL   = sc[np - 1];
    const float L    = cL - c0;
    const float ghost = L / 1000.0f;
    const float inv_h = (float)(np - 1) / L;
    const float wd0  = w_dd[0];
    const float wd1  = w_dd[1];
    const int   jmax = np - 2;   // last interval index [sc[jmax], sc[jmax+1]]

    const int i4 = blockIdx.x * blockDim.x + threadIdx.x;
    const int base = i4 << 2;
    if (base >= n) return;

    float xs[4];
    bool full = (base + 3 < n);
    if (full) {
        float4 xv = ((const float4*)x)[i4];
        xs[0] = xv.x; xs[1] = xv.y; xs[2] = xv.z; xs[3] = xv.w;
    } else {
        #pragma unroll
        for (int k = 0; k < 4; ++k) xs[k] = (base + k < n) ? x[base + k] : 0.0f;
    }

    float r[4];
    #pragma unroll
    for (int k = 0; k < 4; ++k) {
        float xf = xs[k];
        // locate containing interval j: sc[j] <= xf <= sc[j+1]
        int j = (int)floorf((xf - c0) * inv_h);
        j = min(max(j, 0), jmax);
        if (j < jmax && xf > sc[j + 1]) ++j;
        else if (j > 0 && xf < sc[j])   --j;

        float u = 0.0f;
        // interior hat centered at node j (basis index j-1), support [sc[j-1], sc[j+1]]
        if (j >= 1)
            u += sw[j - 1] * hatf(xf, sc[j - 1], sc[j], sc[j + 1]);
        // interior hat centered at node j+1 (basis index j), support [sc[j], sc[j+2]]
        if (j <= jmax - 1)
            u += sw[j] * hatf(xf, sc[j], sc[j + 1], sc[j + 2]);
        // boundary hats
        if (j == 0)
            u += wd0 * hatf(xf, c0 - ghost, c0, sc[1]);
        if (j == jmax)
            u += wd1 * hatf(xf, sc[np - 2], cL, cL + ghost);
        r[k] = u;
    }

    if (full) {
        ((float4*)out)[i4] = make_float4(r[0], r[1], r[2], r[3]);
    } else {
        #pragma unroll
        for (int k = 0; k < 4; ++k)
            if (base + k < n) out[base + k] = r[k];
    }
}

extern "C" void kernel_launch(void* const* d_in, const int* in_sizes, int n_in,
                              void* d_out, int out_size, void* d_ws, size_t ws_size,
                              hipStream_t stream) {
    const float* x      = (const float*)d_in[0];
    const float* coords = (const float*)d_in[1];
    const float* w_uu   = (const float*)d_in[2];
    const float* w_dd   = (const float*)d_in[3];
    float* out = (float*)d_out;

    const int n  = in_sizes[0];   // 262144
    const int np = in_sizes[1];   // 512

    const int n4    = (n + 3) >> 2;
    const int block = 256;
    const int grid  = (n4 + block - 1) / block;
    const size_t smem = (size_t)(np + (np - 2)) * sizeof(float);

    MeshNN_23330262352119_kernel<<<grid, block, smem, stream>>>(
        x, coords, w_uu, w_dd, out, n, np);
}

// Round 2
// 62.817 us; speedup vs baseline: 1.0016x; 1.0016x over previous
//
#include <hip/hip_runtime.h>

__device__ __forceinline__ float relu_f(float v) { return fmaxf(v, 0.0f); }

// Exact replica of the reference _hat() in fp32.
__device__ __forceinline__ float hatf(float xf, float xm, float xc, float xp) {
    float left  = relu_f(1.0f - relu_f(xc - xf) / (xc - xm));
    float right = relu_f(1.0f - relu_f(xf - xc) / (xp - xc));
    return left + right - 1.0f;
}

__global__ __launch_bounds__(256) void MeshNN_23330262352119_kernel(
        const float* __restrict__ x,
        const float* __restrict__ coords,
        const float* __restrict__ w_uu,
        const float* __restrict__ w_dd,
        float* __restrict__ out,
        int n, int np) {
    extern __shared__ float smem[];
    float* sc = smem;          // np node coords
    float* sw = smem + np;     // np-2 interior weights
    // 256 threads stage 512+510 floats: 4 iterations total, then barrier.
    for (int i = threadIdx.x; i < np; i += blockDim.x)     sc[i] = coords[i];
    for (int i = threadIdx.x; i < np - 2; i += blockDim.x) sw[i] = w_uu[i];
    __syncthreads();

    const float c0    = sc[0];
    const float cL    = sc[np - 1];
    const float L     = cL - c0;
    const float ghost = L / 1000.0f;
    const float inv_h = (float)(np - 1) / L;
    const float wd0   = w_dd[0];   // wave-uniform -> s_load
    const float wd1   = w_dd[1];
    const int   jmax  = np - 2;    // last interval index [sc[jmax], sc[jmax+1]]

    const int i2   = blockIdx.x * blockDim.x + threadIdx.x;
    const int base = i2 << 1;
    if (base + 1 >= n) {
        // tail guard (not taken at n=262144, but safe)
        if (base < n) {
            float xf = x[base];
            int j = (int)floorf((xf - c0) * inv_h);
            j = min(max(j, 0), jmax);
            if (j < jmax && xf > sc[j + 1]) ++j;
            else if (j > 0 && xf < sc[j])   --j;
            float u = 0.0f;
            if (j >= 1)        u += sw[j - 1] * hatf(xf, sc[j - 1], sc[j], sc[j + 1]);
            if (j <= jmax - 1) u += sw[j]     * hatf(xf, sc[j], sc[j + 1], sc[j + 2]);
            if (j == 0)        u += wd0 * hatf(xf, c0 - ghost, c0, sc[1]);
            if (j == jmax)     u += wd1 * hatf(xf, sc[np - 2], cL, cL + ghost);
            out[base] = u;
        }
        return;
    }

    float2 xv = ((const float2*)x)[i2];
    float xs[2] = {xv.x, xv.y};
    float r[2];

    #pragma unroll
    for (int k = 0; k < 2; ++k) {
        float xf = xs[k];
        // locate containing interval j: sc[j] <= xf <= sc[j+1]
        int j = (int)floorf((xf - c0) * inv_h);
        j = min(max(j, 0), jmax);
        if (j < jmax && xf > sc[j + 1]) ++j;
        else if (j > 0 && xf < sc[j])   --j;

        float u = 0.0f;
        // interior hat centered at node j (basis index j-1), support [sc[j-1], sc[j+1]]
        if (j >= 1)
            u += sw[j - 1] * hatf(xf, sc[j - 1], sc[j], sc[j + 1]);
        // interior hat centered at node j+1 (basis index j), support [sc[j], sc[j+2]]
        if (j <= jmax - 1)
            u += sw[j] * hatf(xf, sc[j], sc[j + 1], sc[j + 2]);
        // boundary hats
        if (j == 0)
            u += wd0 * hatf(xf, c0 - ghost, c0, sc[1]);
        if (j == jmax)
            u += wd1 * hatf(xf, sc[np - 2], cL, cL + ghost);
        r[k] = u;
    }

    ((float2*)out)[i2] = make_float2(r[0], r[1]);
}

extern "C" void kernel_launch(void* const* d_in, const int* in_sizes, int n_in,
                              void* d_out, int out_size, void* d_ws, size_t ws_size,
                              hipStream_t stream) {
    const float* x      = (const float*)d_in[0];
    const float* coords = (const float*)d_in[1];
    const float* w_uu   = (const float*)d_in[2];
    const float* w_dd   = (const float*)d_in[3];
    float* out = (float*)d_out;

    const int n  = in_sizes[0];   // 262144
    const int np = in_sizes[1];   // 512

    const int n2    = (n + 1) >> 1;
    const int block = 256;
    const int grid  = (n2 + block - 1) / block;   // 512 blocks -> 2 blocks/CU, 8 waves/CU
    const size_t smem = (size_t)(np + (np - 2)) * sizeof(float);

    MeshNN_23330262352119_kernel<<<grid, block, smem, stream>>>(
        x, coords, w_uu, w_dd, out, n, np);
}